// Round 13
// baseline (40.529 us; speedup 1.0000x reference)
//
#include <hip/hip_runtime.h>
#include <cstdint>
#include <cstddef>

// Problem constants (reference: N=8192, C=1000, A=768)
// KEY IDENTITY: sigma2[n,c] = ratio * sum_a (W[c,a]-W[l,a])^2 cv[l,a] depends
// on n only through l = labels[n]. Compute G[l,c] once (1024^2) and gather.
// t3 (row-constant) cancels in log-softmax; dropped.
#define N_SAMPLES 8192
#define N_CLASSES 1000
#define C_PAD     1024
#define A_DIM     768
#define K_DIM     1536   // 2*A  (virtual concat [cv ; -2*W*cv] x [W^2 ; W])
#define BT 64            // G-GEMM tile (64x64)
#define BK 64
#define NT (K_DIM / BK)  // 24 K-steps; kt<12 -> first half, kt>=12 -> second

typedef __attribute__((ext_vector_type(8))) __bf16 bf16x8;
typedef __attribute__((ext_vector_type(4))) float  f32x4;

#define WAIT_VM0   do { asm volatile("s_waitcnt vmcnt(0)" ::: "memory"); \
                        __builtin_amdgcn_sched_barrier(0); } while (0)
#define WAIT_LGKM0 do { asm volatile("s_waitcnt lgkmcnt(0)" ::: "memory"); \
                        __builtin_amdgcn_sched_barrier(0); } while (0)

// ---- G-GEMM with FUSED prep: stages f32 W/CV, converts to bf16 in-register,
// ds_writes swizzled (write chunk g^(row&7) == read-side swch involution).
// 64x64 tile, 512 thr (8 waves 4x2, each 16x32), grid 256, 2-buffer 2-phase
// reg-staged pipeline (T14), one barrier/iter.  [verified R11/R12, absmax 0.0]
// Also zeroes out[0] for softmax's per-block atomic accumulation.
__global__ __launch_bounds__(512, 2) void gemm_g(
        const float* __restrict__ W, const float* __restrict__ CV,
        __bf16* __restrict__ G, float* __restrict__ out) {
    __shared__ __align__(16) __bf16 As[2][BT * BK];   // 2 x 8 KB
    __shared__ __align__(16) __bf16 Bs[2][BT * BK];   // 2 x 8 KB
    int tid  = threadIdx.x;
    int lane = tid & 63;
    int wave = tid >> 6;
    if (blockIdx.x == 0 && tid == 0) out[0] = 0.f;    // visible to next kernel
                                                      // via stream release/acquire
    // XCD-chunked bijective swizzle: 256 blocks, 8 XCDs, 32 blocks/XCD.
    int wgid = (blockIdx.x & 7) * 32 + (blockIdx.x >> 3);
    int rowBase = (wgid >> 4) * BT;      // 16 row tiles (l panels)
    int colBase = (wgid & 15) * BT;      // 16 col tiles (c panels)
    int wr = wave >> 1;                  // 4x2 wave grid, each wave 16x32
    int wc = wave & 1;

    // staging geometry: 512 chunks (16B) per tile, 1 chunk/thread.
    int row = tid >> 3;                  // tile row 0..63
    int g   = tid & 7;                   // global 8-elem chunk in row
    int wsoff = row * (BK * 2) + ((g ^ (row & 7)) * 16);   // swizzled LDS byte
    int rA = rowBase + row;              // l index for A staging
    int rB = colBase + row;              // c index for B staging
    bool vA = rA < N_CLASSES;
    bool vB = rB < N_CLASSES;
    int cA = vA ? rA : N_CLASSES - 1;    // clamp: no OOB reads of W/CV
    int cB = vB ? rB : N_CLASSES - 1;

    f32x4 acc[2];
    acc[0] = (f32x4){0.f, 0.f, 0.f, 0.f};
    acc[1] = (f32x4){0.f, 0.f, 0.f, 0.f};

    f32x4 ra[2], rwA[2], rbW[2];         // staged f32 (CV_A, W_A, W_B)
    #pragma unroll
    for (int i = 0; i < 2; ++i) {
        ra[i] = (f32x4){0,0,0,0}; rwA[i] = (f32x4){0,0,0,0}; rbW[i] = (f32x4){0,0,0,0};
    }

    auto stageLoad = [&](int kt) {       // issue global f32 loads for tile kt
        bool half = kt >= 12;
        int aoff = (half ? (kt - 12) : kt) * 64 + g * 8;
        const float* cvp = CV + (size_t)cA * A_DIM + aoff;
        ra[0] = *reinterpret_cast<const f32x4*>(cvp);
        ra[1] = *reinterpret_cast<const f32x4*>(cvp + 4);
        const float* wbp = W + (size_t)cB * A_DIM + aoff;
        rbW[0] = *reinterpret_cast<const f32x4*>(wbp);
        rbW[1] = *reinterpret_cast<const f32x4*>(wbp + 4);
        if (half) {
            const float* wap = W + (size_t)cA * A_DIM + aoff;
            rwA[0] = *reinterpret_cast<const f32x4*>(wap);
            rwA[1] = *reinterpret_cast<const f32x4*>(wap + 4);
        }
    };
    auto convWrite = [&](int kt, int b) {   // convert + swizzled ds_write
        bool half = kt >= 12;
        bf16x8 av, bv;
        #pragma unroll
        for (int j = 0; j < 8; ++j) {
            float cv = ra[j >> 2][j & 3];
            float wa = rwA[j >> 2][j & 3];
            float wb = rbW[j >> 2][j & 3];
            float aval = half ? (-2.0f * wa * cv) : cv;
            float bval = half ? wb : (wb * wb);
            av[j] = vA ? (__bf16)aval : (__bf16)0.f;
            bv[j] = vB ? (__bf16)bval : (__bf16)0.f;
        }
        *reinterpret_cast<bf16x8*>((char*)&As[b][0] + wsoff) = av;
        *reinterpret_cast<bf16x8*>((char*)&Bs[b][0] + wsoff) = bv;
    };
    auto loadFrags = [&](int b, int kk, bf16x8* af, bf16x8* bf) {
        int swch = ((kk * 4 + (lane >> 4)) ^ (lane & 7)) * 8;   // verified R2/R6
        int r = wr * 16 + (lane & 15);
        af[0] = *reinterpret_cast<const bf16x8*>(&As[b][r * BK + swch]);
        #pragma unroll
        for (int n = 0; n < 2; ++n) {
            int c = wc * 32 + n * 16 + (lane & 15);
            bf[n] = *reinterpret_cast<const bf16x8*>(&Bs[b][c * BK + swch]);
        }
    };

    // prologue: stage tile 0
    stageLoad(0);
    WAIT_VM0;
    convWrite(0, 0);
    WAIT_LGKM0;
    __builtin_amdgcn_s_barrier();

    for (int kt = 0; kt < NT; ++kt) {
        int bR = kt & 1;
        bool st = (kt + 1) < NT;
        if (st) stageLoad(kt + 1);       // VMEM in flight during compute
        bf16x8 af0[1], bf0[2], af1[1], bf1[2];
        loadFrags(bR, 0, af0, bf0);
        loadFrags(bR, 1, af1, bf1);
        WAIT_LGKM0;
        __builtin_amdgcn_s_setprio(1);
        acc[0] = __builtin_amdgcn_mfma_f32_16x16x32_bf16(af0[0], bf0[0], acc[0], 0, 0, 0);
        acc[1] = __builtin_amdgcn_mfma_f32_16x16x32_bf16(af0[0], bf0[1], acc[1], 0, 0, 0);
        acc[0] = __builtin_amdgcn_mfma_f32_16x16x32_bf16(af1[0], bf1[0], acc[0], 0, 0, 0);
        acc[1] = __builtin_amdgcn_mfma_f32_16x16x32_bf16(af1[0], bf1[1], acc[1], 0, 0, 0);
        __builtin_amdgcn_s_setprio(0);
        if (st) {
            WAIT_VM0;                    // staged regs landed (hidden by MFMA)
            convWrite(kt + 1, bR ^ 1);   // buf^1 free since barrier of kt-1
        }
        WAIT_LGKM0;                      // my ds_writes (and reads) retired
        __builtin_amdgcn_s_barrier();    // writes visible; reads of bR done
    }

    // epilogue: C/D layout col=lane&15, row=(lane>>4)*4+j [verified m89/m91]
    int lr = (lane >> 4) * 4;
    int lc = lane & 15;
    #pragma unroll
    for (int n = 0; n < 2; ++n) {
        int gr0 = rowBase + wr * 16 + lr;
        int gc  = colBase + wc * 32 + n * 16 + lc;
        #pragma unroll
        for (int j = 0; j < 4; ++j)
            G[(size_t)(gr0 + j) * C_PAD + gc] = (__bf16)acc[n][j];
    }
}

// ------- fused: aug = logits + h*G[label]; log-softmax NLL; block partial ---
// 256 blocks x 512 thr; each wave handles 4 samples sequentially (2048 waves,
// 8/CU). ONE same-address atomicAdd per block: 256 atomics spread over the
// kernel's ~8 us >> 9 ns service rate -> no queueing (R11 lesson quantified:
// 2048 bunched atomics = +19 us; 256 spread = ~0). No fences (R5 lesson).
__global__ __launch_bounds__(512) void softmax_loss(
        const __bf16* __restrict__ G,
        const float* __restrict__ logits,
        const float* __restrict__ ratiop,
        const int* __restrict__ labels,
        float* __restrict__ out) {
    int tid  = threadIdx.x;
    int lane = tid & 63;
    int wv   = tid >> 6;
    float h  = 0.5f * ratiop[0];
    float wloss = 0.f;                   // lane-0 accumulator

    #pragma unroll
    for (int it = 0; it < 4; ++it) {
        int gw = blockIdx.x * 32 + wv * 4 + it;   // 0..8191
        int lab = labels[gw];            // wave-uniform -> scalar load
        const __bf16* rowp = G + (size_t)lab * C_PAD;
        const float*  lrow = logits + (size_t)gw * N_CLASSES;

        bf16x8 v0 = *reinterpret_cast<const bf16x8*>(rowp + lane * 8);
        bf16x8 v1 = *reinterpret_cast<const bf16x8*>(rowp + 512 + lane * 8);
        f32x4 l0a = __builtin_nontemporal_load(reinterpret_cast<const f32x4*>(lrow + lane * 8));
        f32x4 l0b = __builtin_nontemporal_load(reinterpret_cast<const f32x4*>(lrow + lane * 8 + 4));
        f32x4 l1a = {0.f,0.f,0.f,0.f}, l1b = {0.f,0.f,0.f,0.f};
        if (lane < 61) {             // cols 512+lane*8..+7 < 1000 iff lane < 61
            l1a = __builtin_nontemporal_load(reinterpret_cast<const f32x4*>(lrow + 512 + lane * 8));
            l1b = __builtin_nontemporal_load(reinterpret_cast<const f32x4*>(lrow + 512 + lane * 8 + 4));
        }
        float f[16];
        #pragma unroll
        for (int j = 0; j < 4; ++j) {
            f[j]     = l0a[j] + h * (float)v0[j];
            f[4 + j] = l0b[j] + h * (float)v0[4 + j];
        }
        #pragma unroll
        for (int j = 0; j < 4; ++j) {
            f[8 + j]  = (lane < 61) ? l1a[j] + h * (float)v1[j]     : -1e30f;
            f[12 + j] = (lane < 61) ? l1b[j] + h * (float)v1[4 + j] : -1e30f;
        }
        float m = -1e30f;
        #pragma unroll
        for (int j = 0; j < 16; ++j) m = fmaxf(m, f[j]);
        #pragma unroll
        for (int s = 32; s > 0; s >>= 1) m = fmaxf(m, __shfl_xor(m, s));
        float sum = 0.f;
        #pragma unroll
        for (int j = 0; j < 16; ++j) sum += __expf(f[j] - m);
        #pragma unroll
        for (int s = 32; s > 0; s >>= 1) sum += __shfl_xor(sum, s);
        if (lane == 0) {
            float tv = lrow[lab] + h * (float)rowp[lab];
            wloss += logf(sum) + m - tv;
        }
    }

    __shared__ float red[8];
    if (lane == 0) red[wv] = wloss;
    __syncthreads();
    if (tid == 0) {
        float s = 0.f;
        #pragma unroll
        for (int w = 0; w < 8; ++w) s += red[w];
        atomicAdd(out, s * (1.0f / (float)N_SAMPLES));
    }
}

extern "C" void kernel_launch(void* const* d_in, const int* in_sizes, int n_in,
                              void* d_out, int out_size, void* d_ws, size_t ws_size,
                              hipStream_t stream) {
    const float* W      = (const float*)d_in[0];   // fc_weight [C, A]
    // d_in[1] = features [N, A] — unused by the reference math
    const float* logits = (const float*)d_in[2];   // [N, C]
    const int*   labels = (const int*)d_in[3];     // [N]
    const float* ratio  = (const float*)d_in[4];   // scalar
    const float* CV     = (const float*)d_in[5];   // cv_matrix [C, A]
    // d_in[6] = manner — unused

    // workspace: just G (2 MB)
    __bf16* G = (__bf16*)d_ws;                     // [1024][1024] bf16

    gemm_g<<<256, 512, 0, stream>>>(W, CV, G, (float*)d_out);
    softmax_loss<<<256, 512, 0, stream>>>(G, logits, ratio, labels, (float*)d_out);
}

// Round 14
// 38.126 us; speedup vs baseline: 1.0630x; 1.0630x over previous
//
#include <hip/hip_runtime.h>
#include <cstdint>
#include <cstddef>

// Problem constants (reference: N=8192, C=1000, A=768)
// KEY IDENTITY: sigma2[n,c] = ratio * sum_a (W[c,a]-W[l,a])^2 cv[l,a] depends
// on n only through l = labels[n]. Compute G[l,c] once (1024^2) and gather.
// t3 (row-constant) cancels in log-softmax; dropped.
#define N_SAMPLES 8192
#define N_CLASSES 1000
#define C_PAD     1024
#define A_DIM     768
#define K_DIM     1536   // 2*A  (concatenated [cv ; -2*W*cv] / [W^2 ; W])
#define BT 64            // G-GEMM tile (64x64)
#define BK 64
#define NT (K_DIM / BK)  // 24 K-steps

typedef __attribute__((ext_vector_type(8))) __bf16 bf16x8;
typedef __attribute__((ext_vector_type(4))) __bf16 bf16x4;
typedef __attribute__((ext_vector_type(4))) float  f32x4;

#define WAIT_VM(N) do { asm volatile("s_waitcnt vmcnt(" #N ")" ::: "memory"); \
                        __builtin_amdgcn_sched_barrier(0); } while (0)
#define WAIT_LGKM0 do { asm volatile("s_waitcnt lgkmcnt(0)" ::: "memory"); \
                        __builtin_amdgcn_sched_barrier(0); } while (0)

// ---- prep: waves 0..1023 build UVc rows; waves 1024..2047 build Wcat rows --
__global__ void prep(const float* __restrict__ W, const float* __restrict__ CV,
                     __bf16* __restrict__ UVc, __bf16* __restrict__ Wcat) {
    int gw   = (blockIdx.x * blockDim.x + threadIdx.x) >> 6;
    int lane = threadIdx.x & 63;
    bf16x4 z = {(__bf16)0.f, (__bf16)0.f, (__bf16)0.f, (__bf16)0.f};
    if (gw < C_PAD) {
        int l = gw;
        if (l < N_CLASSES) {
            #pragma unroll
            for (int p = 0; p < 3; ++p) {
                int a = p * 256 + lane * 4;
                f32x4 wk = *reinterpret_cast<const f32x4*>(W  + (size_t)l * A_DIM + a);
                f32x4 cv = *reinterpret_cast<const f32x4*>(CV + (size_t)l * A_DIM + a);
                bf16x4 u, v;
                #pragma unroll
                for (int j = 0; j < 4; ++j) {
                    u[j] = (__bf16)cv[j];
                    v[j] = (__bf16)(-2.0f * wk[j] * cv[j]);
                }
                *reinterpret_cast<bf16x4*>(UVc + (size_t)l * K_DIM + a)         = u;
                *reinterpret_cast<bf16x4*>(UVc + (size_t)l * K_DIM + A_DIM + a) = v;
            }
        } else {
            #pragma unroll
            for (int p = 0; p < 6; ++p)
                *reinterpret_cast<bf16x4*>(UVc + (size_t)l * K_DIM + p * 256 + lane * 4) = z;
        }
    } else {
        int c = gw - C_PAD;
        if (c < N_CLASSES) {
            #pragma unroll
            for (int p = 0; p < 3; ++p) {
                int a = p * 256 + lane * 4;
                f32x4 w = *reinterpret_cast<const f32x4*>(W + (size_t)c * A_DIM + a);
                bf16x4 sq, li;
                #pragma unroll
                for (int j = 0; j < 4; ++j) { sq[j] = (__bf16)(w[j] * w[j]); li[j] = (__bf16)w[j]; }
                *reinterpret_cast<bf16x4*>(Wcat + (size_t)c * K_DIM + a)         = sq;
                *reinterpret_cast<bf16x4*>(Wcat + (size_t)c * K_DIM + A_DIM + a) = li;
            }
        } else {
            #pragma unroll
            for (int p = 0; p < 6; ++p)
                *reinterpret_cast<bf16x4*>(Wcat + (size_t)c * K_DIM + p * 256 + lane * 4) = z;
        }
    }
}

// ---- G-GEMM: G[l][c] = sum_k UVc[l,k]*Wcat[c,k]   (1024 x 1024 x 1536) -----
// 64x64 tile, 512 thr (8 waves 4x2, each 16x32 -> 2 waves/SIMD), grid 256.
// 3-stage pipeline, m201 phase discipline, counted vmcnt, verified XOR swizzle.
__global__ __launch_bounds__(512, 2) void gemm_g(
        const __bf16* __restrict__ UVc, const __bf16* __restrict__ Wcat,
        __bf16* __restrict__ G) {
    __shared__ __align__(16) __bf16 As[3][BT * BK];   // 3 x 8 KB
    __shared__ __align__(16) __bf16 Bs[3][BT * BK];   // 3 x 8 KB
    int tid  = threadIdx.x;
    int lane = tid & 63;
    int wave = tid >> 6;
    // XCD-chunked bijective swizzle: 256 blocks, 8 XCDs, 32 blocks/XCD.
    int wgid = (blockIdx.x & 7) * 32 + (blockIdx.x >> 3);
    int rowBase = (wgid >> 4) * BT;      // 16 row tiles
    int colBase = (wgid & 15) * BT;      // 16 col tiles
    int wr = wave >> 1;                  // 4x2 wave grid, each wave 16x32
    int wc = wave & 1;

    f32x4 acc[2];
    acc[0] = (f32x4){0.f, 0.f, 0.f, 0.f};
    acc[1] = (f32x4){0.f, 0.f, 0.f, 0.f};

    auto stageA = [&](int b, int k0) {
        int row  = tid >> 3;             // 0..63
        int scch = (tid & 7) ^ (row & 7);
        int base = tid & ~63;
        const __bf16* ga = UVc + (size_t)(rowBase + row) * K_DIM + k0 + scch * 8;
        __builtin_amdgcn_global_load_lds(
            (const __attribute__((address_space(1))) void*)ga,
            (__attribute__((address_space(3))) void*)((char*)&As[b][0] + (size_t)base * 16),
            16, 0, 0);
    };
    auto stageB = [&](int b, int k0) {
        int row  = tid >> 3;
        int scch = (tid & 7) ^ (row & 7);
        int base = tid & ~63;
        const __bf16* gb = Wcat + (size_t)(colBase + row) * K_DIM + k0 + scch * 8;
        __builtin_amdgcn_global_load_lds(
            (const __attribute__((address_space(1))) void*)gb,
            (__attribute__((address_space(3))) void*)((char*)&Bs[b][0] + (size_t)base * 16),
            16, 0, 0);
    };
    auto loadFrags = [&](int b, int kk, bf16x8* af, bf16x8* bf) {
        int swch = ((kk * 4 + (lane >> 4)) ^ (lane & 7)) * 8;   // verified R2/R6
        int r = wr * 16 + (lane & 15);
        af[0] = *reinterpret_cast<const bf16x8*>(&As[b][r * BK + swch]);
        #pragma unroll
        for (int n = 0; n < 2; ++n) {
            int c = wc * 32 + n * 16 + (lane & 15);
            bf[n] = *reinterpret_cast<const bf16x8*>(&Bs[b][c * BK + swch]);
        }
    };
    auto doMFMA = [&](bf16x8* af, bf16x8* bf) {
        __builtin_amdgcn_s_setprio(1);
        #pragma unroll
        for (int n = 0; n < 2; ++n)
            acc[n] = __builtin_amdgcn_mfma_f32_16x16x32_bf16(
                af[0], bf[n], acc[n], 0, 0, 0);
        __builtin_amdgcn_s_setprio(0);
    };

    stageA(0, 0);        stageB(0, 0);
    stageA(1, BK);       stageB(1, BK);
    WAIT_VM(2);                          // tile 0 landed; tile 1 (2) in flight
    __builtin_amdgcn_s_barrier();

    for (int kt = 0; kt < NT; ++kt) {
        int bR = kt % 3;
        int bS = (kt + 2) % 3;
        bool st = (kt + 2) < NT;
        int k2 = (kt + 2) * BK;
        bf16x8 af[1], bf[2];
        // ---- phase 0 (kk=0)
        loadFrags(bR, 0, af, bf);
        if (st) stageA(bS, k2);
        __builtin_amdgcn_s_barrier();
        WAIT_LGKM0;
        doMFMA(af, bf);
        __builtin_amdgcn_s_barrier();
        // ---- phase 1 (kk=1)
        loadFrags(bR, 1, af, bf);
        if (st) stageB(bS, k2);
        if (st) { WAIT_VM(2); } else { WAIT_VM(0); }
        __builtin_amdgcn_s_barrier();
        WAIT_LGKM0;
        doMFMA(af, bf);
        __builtin_amdgcn_s_barrier();
    }

    // epilogue: C/D layout col=lane&15, row=(lane>>4)*4+j [verified m89/m91]
    int lr = (lane >> 4) * 4;
    int lc = lane & 15;
    #pragma unroll
    for (int n = 0; n < 2; ++n) {
        int gr0 = rowBase + wr * 16 + lr;
        int gc  = colBase + wc * 32 + n * 16 + lc;
        #pragma unroll
        for (int j = 0; j < 4; ++j)
            G[(size_t)(gr0 + j) * C_PAD + gc] = (__bf16)acc[n][j];
    }
}

// ------- fused: aug = logits + h*G[label]; log-softmax NLL at label ---------
// one wave per sample row (4/block, 8192 waves = 32/CU TLP); G row from L2;
// logits nontemporal (read-once, don't evict G). No atomics, no fences.
__global__ void softmax_loss(const __bf16* __restrict__ G,
                             const float* __restrict__ logits,
                             const float* __restrict__ ratiop,
                             const int* __restrict__ labels,
                             float* __restrict__ rowloss) {
    int tid  = threadIdx.x;
    int lane = tid & 63;
    int wv   = tid >> 6;
    int gw   = blockIdx.x * 4 + wv;
    float h  = 0.5f * ratiop[0];
    int  lab = labels[gw];               // wave-uniform -> scalar load
    const __bf16* rowp = G + (size_t)lab * C_PAD;
    const float*  lrow = logits + (size_t)gw * N_CLASSES;

    bf16x8 v0 = *reinterpret_cast<const bf16x8*>(rowp + lane * 8);
    bf16x8 v1 = *reinterpret_cast<const bf16x8*>(rowp + 512 + lane * 8);
    f32x4 l0a = __builtin_nontemporal_load(reinterpret_cast<const f32x4*>(lrow + lane * 8));
    f32x4 l0b = __builtin_nontemporal_load(reinterpret_cast<const f32x4*>(lrow + lane * 8 + 4));
    f32x4 l1a = {0.f,0.f,0.f,0.f}, l1b = {0.f,0.f,0.f,0.f};
    if (lane < 61) {                 // cols 512+lane*8..+7 < 1000 iff lane < 61
        l1a = __builtin_nontemporal_load(reinterpret_cast<const f32x4*>(lrow + 512 + lane * 8));
        l1b = __builtin_nontemporal_load(reinterpret_cast<const f32x4*>(lrow + 512 + lane * 8 + 4));
    }
    float f[16];
    #pragma unroll
    for (int j = 0; j < 4; ++j) {
        f[j]     = l0a[j] + h * (float)v0[j];
        f[4 + j] = l0b[j] + h * (float)v0[4 + j];
    }
    #pragma unroll
    for (int j = 0; j < 4; ++j) {
        f[8 + j]  = (lane < 61) ? l1a[j] + h * (float)v1[j]     : -1e30f;
        f[12 + j] = (lane < 61) ? l1b[j] + h * (float)v1[4 + j] : -1e30f;
    }
    float m = -1e30f;
    #pragma unroll
    for (int j = 0; j < 16; ++j) m = fmaxf(m, f[j]);
    #pragma unroll
    for (int s = 32; s > 0; s >>= 1) m = fmaxf(m, __shfl_xor(m, s));
    float sum = 0.f;
    #pragma unroll
    for (int j = 0; j < 16; ++j) sum += __expf(f[j] - m);
    #pragma unroll
    for (int s = 32; s > 0; s >>= 1) sum += __shfl_xor(sum, s);
    if (lane == 0) {
        float tv = lrow[lab] + h * (float)rowp[lab];
        rowloss[gw] = logf(sum) + m - tv;
    }
}

// ---------------- deterministic final mean (fixed-order, no atomics) --------
__global__ void finalize(const float* __restrict__ rowloss, float* __restrict__ out) {
    int tid = threadIdx.x;
    float part = 0.f;
    #pragma unroll
    for (int i = 0; i < 8; ++i) part += rowloss[i * 1024 + tid];
    #pragma unroll
    for (int s = 32; s > 0; s >>= 1) part += __shfl_xor(part, s);
    __shared__ float tmp[16];
    int lane = tid & 63, wv = tid >> 6;
    if (lane == 0) tmp[wv] = part;
    __syncthreads();
    if (tid == 0) {
        float sum = 0.f;
        #pragma unroll
        for (int w = 0; w < 16; ++w) sum += tmp[w];
        out[0] = sum / (float)N_SAMPLES;
    }
}

extern "C" void kernel_launch(void* const* d_in, const int* in_sizes, int n_in,
                              void* d_out, int out_size, void* d_ws, size_t ws_size,
                              hipStream_t stream) {
    const float* W      = (const float*)d_in[0];   // fc_weight [C, A]
    // d_in[1] = features [N, A] — unused by the reference math
    const float* logits = (const float*)d_in[2];   // [N, C]
    const int*   labels = (const int*)d_in[3];     // [N]
    const float* ratio  = (const float*)d_in[4];   // scalar
    const float* CV     = (const float*)d_in[5];   // cv_matrix [C, A]
    // d_in[6] = manner — unused

    // workspace layout (bytes), total ~8.4 MB
    char* ws = (char*)d_ws;
    __bf16* Wcat    = (__bf16*)(ws + 0);            // 3,145,728 B  [1024][1536] bf16
    __bf16* UVc     = (__bf16*)(ws + 3145728);      // 3,145,728 B  [1024][1536] bf16
    __bf16* G       = (__bf16*)(ws + 6291456);      // 2,097,152 B  [1024][1024] bf16
    float*  rowloss = (float*) (ws + 8388608);      //    32,768 B  [8192] f32

    prep<<<2 * C_PAD / 4, 256, 0, stream>>>(W, CV, UVc, Wcat);
    gemm_g<<<256, 512, 0, stream>>>(UVc, Wcat, G);
    softmax_loss<<<N_SAMPLES / 4, 256, 0, stream>>>(G, logits, ratio, labels, rowloss);
    finalize<<<1, 1024, 0, stream>>>(rowloss, (float*)d_out);
}